// Round 1
// 145.032 us; speedup vs baseline: 1.0984x; 1.0984x over previous
//
#include <hip/hip_runtime.h>
#include <hip/hip_bf16.h>

// Problem constants
#define B_  4096
#define T_  80
#define E_  100
#define U_  64
#define G_  256    // 4*U
#define V_  10000

#define S_H  72    // hbuf row stride (bf16 elems), 144B rows (16B aligned)
#define AS   136   // embk A-tile LDS stride (bf16): 272B rows, 16B aligned, %8==0

typedef __attribute__((ext_vector_type(8))) __bf16 bf16x8;
typedef __attribute__((ext_vector_type(4))) __bf16 bf16x4;
typedef __attribute__((ext_vector_type(4))) float  floatx4;

__device__ __forceinline__ float sigmoidf_(float x) {
    // rcp(1 + exp2(-log2e * x)) : v_mul, v_exp, v_add, v_rcp
    return __builtin_amdgcn_rcpf(1.f + __expf(-x));
}

__device__ __forceinline__ float tanhf_(float x) {
    // 1 - 2/(e^{2x}+1): monotone, saturates correctly, no NaN
    // v_mul, v_exp, v_add, v_rcp, v_fma
    return fmaf(-2.f, __builtin_amdgcn_rcpf(__expf(2.f * x) + 1.f), 1.f);
}

// Block-wide barrier WITHOUT the vmcnt(0) drain __syncthreads() forces.
// Only LDS traffic (h writes) must be visible across waves per step; the
// embk gather loads are thread-private VGPR fills whose completion is
// tracked by the compiler's own counted s_waitcnt vmcnt(N) at first use.
// __syncthreads()'s implicit "s_waitcnt vmcnt(0)" before s_barrier was
// draining the 2-step-deep prefetch every step (~900cy exposed L2/L3
// gather latency per step on 1-wave/SIMD occupancy).
__device__ __forceinline__ void block_sync_lgkm() {
    asm volatile("s_waitcnt lgkmcnt(0)\n\ts_barrier" ::: "memory");
}

// ---------------------------------------------------------------------------
// Kernel A (MFMA): embk[v][g] = b1[g] + emb[v] . k1[:,g]   (unchanged, known-good)
// ---------------------------------------------------------------------------
__global__ __launch_bounds__(256) void embk_kernel(const float* __restrict__ emb,
                                                   const float* __restrict__ k1,
                                                   const float* __restrict__ b1,
                                                   float* __restrict__ embk) {
    __shared__ __bf16 aLDS[64 * AS];         // 17.4 KB

    const int tid  = threadIdx.x;
    const int lane = tid & 63;
    const int w    = tid >> 6;               // wave: owns cols n0 + [w*32, w*32+32)
    const int n    = lane & 15;
    const int kg   = lane >> 4;
    const int v0   = (blockIdx.x >> 1) * 64;
    const int n0   = (blockIdx.x & 1) * 128;
    const int nrows = min(64, V_ - v0);

    for (int i = tid; i < 64 * AS / 8; i += 256) {
        bf16x8 z;
#pragma unroll
        for (int jj = 0; jj < 8; ++jj) z[jj] = (__bf16)0.f;
        *(bf16x8*)(aLDS + i * 8) = z;
    }

    bf16x8 bfr[2][4];
#pragma unroll
    for (int ct = 0; ct < 2; ++ct)
#pragma unroll
        for (int kc = 0; kc < 4; ++kc) {
            bf16x8 s;
#pragma unroll
            for (int jj = 0; jj < 8; ++jj) {
                int k = kc * 32 + kg * 8 + jj;
                s[jj] = (k < E_) ? (__bf16)k1[k * G_ + n0 + w * 32 + ct * 16 + n]
                                 : (__bf16)0.f;
            }
            bfr[ct][kc] = s;
        }
    const float bv0 = b1[n0 + w * 32 + n];
    const float bv1 = b1[n0 + w * 32 + 16 + n];

    __syncthreads();                         // zeroing done

    for (int i = tid; i < nrows * 25; i += 256) {
        int r = i / 25, q = i - r * 25;
        float4 ev = *(const float4*)(emb + (long)(v0 + r) * E_ + q * 4);
        bf16x4 bv; bv[0] = (__bf16)ev.x; bv[1] = (__bf16)ev.y;
                   bv[2] = (__bf16)ev.z; bv[3] = (__bf16)ev.w;
        *(bf16x4*)(aLDS + r * AS + q * 4) = bv;
    }
    __syncthreads();

#pragma unroll
    for (int mt = 0; mt < 4; ++mt) {
        const __bf16* ab = aLDS + (mt * 16 + n) * AS + kg * 8;
        bf16x8 a0 = *(const bf16x8*)(ab + 0);
        bf16x8 a1 = *(const bf16x8*)(ab + 32);
        bf16x8 a2 = *(const bf16x8*)(ab + 64);
        bf16x8 a3 = *(const bf16x8*)(ab + 96);
#pragma unroll
        for (int ct = 0; ct < 2; ++ct) {
            float bv = ct ? bv1 : bv0;
            floatx4 acc = {bv, bv, bv, bv};
            acc = __builtin_amdgcn_mfma_f32_16x16x32_bf16(a0, bfr[ct][0], acc, 0, 0, 0);
            acc = __builtin_amdgcn_mfma_f32_16x16x32_bf16(a1, bfr[ct][1], acc, 0, 0, 0);
            acc = __builtin_amdgcn_mfma_f32_16x16x32_bf16(a2, bfr[ct][2], acc, 0, 0, 0);
            acc = __builtin_amdgcn_mfma_f32_16x16x32_bf16(a3, bfr[ct][3], acc, 0, 0, 0);
#pragma unroll
            for (int r = 0; r < 4; ++r) {
                int v = v0 + mt * 16 + kg * 4 + r;
                if (v < V_) embk[(long)v * G_ + n0 + w * 32 + ct * 16 + n] = acc[r];
            }
        }
    }
}

// ---------------------------------------------------------------------------
// Kernel B: recurrence via TRANSPOSED MFMA: z^T = r1^T @ h^T.
// 256 blocks x 256 threads (4 waves = 1/SIMD). Block = 16 batch rows; wave w
// owns units [w*16, w*16+16). Per-step sync is a raw s_barrier preceded only
// by lgkmcnt(0): the h ds_write must be visible, but the embk gather loads
// stay IN FLIGHT across the barrier so the 2-step prefetch window actually
// hides the ~400-900cy L2/L3 gather latency (previously __syncthreads'
// vmcnt(0) drain serialized it into every step).
// ---------------------------------------------------------------------------
__global__ __launch_bounds__(256) void lstm_kernel(const int*   __restrict__ tokens,
                                                   const float* __restrict__ embk,
                                                   const float* __restrict__ r1,
                                                   const float* __restrict__ Wd,
                                                   const float* __restrict__ bd,
                                                   float* __restrict__ out) {
    __shared__ int    tokLDS[16 * T_];       // 5.12 KB
    __shared__ __bf16 hbuf[2][16 * S_H];     // 4.6 KB

    const int tid  = threadIdx.x;
    const int lane = tid & 63;
    const int w    = tid >> 6;               // unit block [w*16, w*16+16)
    const int n    = lane & 15;              // batch row (N-operand of MFMA)
    const int kg   = lane >> 4;              // 0..3
    const int bb   = blockIdx.x * 16;

    for (int i = tid; i < 16 * T_; i += 256) tokLDS[i] = tokens[bb * T_ + i];
    for (int i = tid; i < 2 * 16 * S_H; i += 256) (&hbuf[0][0])[i] = (__bf16)0.f;

    // A-fragments = r1^T (static): tile ct covers gate-cols ct*64 + w*16 + m,
    // A[m][k] = r1[k][ct*64 + w*16 + m]; lane holds m = n, k = kc*32 + kg*8 + jj
    bf16x8 afr[4][2];
#pragma unroll
    for (int ct = 0; ct < 4; ++ct)
#pragma unroll
        for (int kc = 0; kc < 2; ++kc) {
            bf16x8 s;
#pragma unroll
            for (int jj = 0; jj < 8; ++jj)
                s[jj] = (__bf16)r1[(kc * 32 + kg * 8 + jj) * G_ + ct * 64 + w * 16 + n];
            afr[ct][kc] = s;
        }

    // cell state: 4 cells/lane: (row n, unit w*16 + 4*kg + r)
    float c[4] = {0.f, 0.f, 0.f, 0.f};

    __syncthreads();                         // tokens + zeroed hbuf visible (once)

    // xk prefetch, 2 steps deep: xkb[s][ct] = embk[tok[n][s]][ct*64 + w*16 + 4kg .. +3]
    floatx4 xkb[2][4];
#pragma unroll
    for (int s = 0; s < 2; ++s) {
        const float* base = embk + (long)tokLDS[n * T_ + s] * G_ + w * 16 + kg * 4;
#pragma unroll
        for (int ct = 0; ct < 4; ++ct)
            xkb[s][ct] = *(const floatx4*)(base + ct * 64);
    }

    auto step = [&](int t, int sel) {        // sel = t & 1 (constant at call site)
        // B-fragments = h^T_{t-1}: B[k][n] = h[n][k]; lane reads row n,
        // units kg*8..kg*8+7 (b0) and 32+kg*8..+7 (b1)
        const __bf16* hb = hbuf[sel ^ 1];
        bf16x8 b0 = *(const bf16x8*)(hb + n * S_H + kg * 8);
        bf16x8 b1 = *(const bf16x8*)(hb + n * S_H + 32 + kg * 8);

        // z^T tiles: acc[ct] = r1^T @ h^T + xk  (C-init = prefetched xk)
        floatx4 acc[4];
#pragma unroll
        for (int ct = 0; ct < 4; ++ct) {
            floatx4 a = xkb[sel][ct];
            a = __builtin_amdgcn_mfma_f32_16x16x32_bf16(afr[ct][0], b0, a, 0, 0, 0);
            a = __builtin_amdgcn_mfma_f32_16x16x32_bf16(afr[ct][1], b1, a, 0, 0, 0);
            acc[ct] = a;
        }

        // prefetch xk for t+2 into the slot just consumed (2-step window)
        if (t + 2 < T_) {
            const float* base = embk + (long)tokLDS[n * T_ + t + 2] * G_ + w * 16 + kg * 4;
#pragma unroll
            for (int ct = 0; ct < 4; ++ct)
                xkb[sel][ct] = *(const floatx4*)(base + ct * 64);
        }

        // gates: 4 dense cells/lane; acc[0]=i, acc[1]=f, acc[2]=g, acc[3]=o
        bf16x4 hv;
#pragma unroll
        for (int r = 0; r < 4; ++r) {
            float zi = acc[0][r], zf = acc[1][r], zg = acc[2][r], zo = acc[3][r];
            float cn = fmaf(sigmoidf_(zf), c[r], sigmoidf_(zi) * tanhf_(zg));
            float hn = sigmoidf_(zo) * tanhf_(cn);
            c[r] = cn;
            hv[r] = (__bf16)hn;
        }
        // h_new: 4 consecutive units -> one b64 write
        *(bf16x4*)(&hbuf[sel][0] + n * S_H + w * 16 + kg * 4) = hv;

        block_sync_lgkm();                   // h_t visible; gathers stay in flight
    };

    for (int t = 0; t < T_; t += 2) {
        step(t,     0);
        step(t + 1, 1);
    }

    // out[b] = sigmoid(h_final[b] . Wd + bd); h_79 in hbuf[1]
    if (tid < 16) {
        const __bf16* hb = hbuf[1] + tid * S_H;
        float s = bd[0];
#pragma unroll
        for (int u = 0; u < U_; ++u) s = fmaf((float)hb[u], Wd[u], s);
        out[bb + tid] = sigmoidf_(s);
    }
}

// ---------------------------------------------------------------------------
extern "C" void kernel_launch(void* const* d_in, const int* in_sizes, int n_in,
                              void* d_out, int out_size, void* d_ws, size_t ws_size,
                              hipStream_t stream) {
    const int*   tokens = (const int*)  d_in[0];
    const float* emb    = (const float*)d_in[1];
    // d_in[2..4] = k0, r0, b0 : dead in the reference (cell0 state unused)
    const float* k1     = (const float*)d_in[5];
    const float* r1     = (const float*)d_in[6];
    const float* b1     = (const float*)d_in[7];
    const float* Wd     = (const float*)d_in[8];
    const float* bd     = (const float*)d_in[9];
    float*       out    = (float*)d_out;

    float* embk = (float*)d_ws;              // V_*G_ floats = 10.24 MB

    embk_kernel<<<((V_ + 63) / 64) * 2, 256, 0, stream>>>(emb, k1, b1, embk);
    lstm_kernel<<<B_ / 16, 256, 0, stream>>>(tokens, embk, r1, Wd, bd, out);
}